// Round 1
// baseline (1007.983 us; speedup 1.0000x reference)
//
#include <hip/hip_runtime.h>
#include <hip/hip_bf16.h>

// Problem constants (from reference)
#define NS   16384   // samples
#define NC   64      // components (M)
#define DIN  128     // K
#define DOUT 128     // Q
#define NSP  8       // species

typedef __attribute__((ext_vector_type(8))) short short8;   // 8 bf16 = 4 VGPRs (MFMA A/B frag)
typedef __attribute__((ext_vector_type(4))) float f32x4;    // MFMA C/D frag

// ---------------------------------------------------------------------------
// Kernel 1: W [8][128][128] fp32  ->  Wt [8][q][d] bf16 (transposed, RNE)
// Reads coalesced along q; scattered 2B writes land in L2 (256 KB footprint).
// ---------------------------------------------------------------------------
__global__ void wt_transpose_kernel(const float* __restrict__ W,
                                    __hip_bfloat16* __restrict__ Wt) {
    int idx = blockIdx.x * 256 + threadIdx.x;      // ordered (s, d, q): coalesced read
    int q = idx & 127;
    int d = (idx >> 7) & 127;
    int s = idx >> 14;
    float v = W[idx];                              // W[s][d][q]
    Wt[s * (DIN * DOUT) + q * DIN + d] = __float2bfloat16(v);
}

// ---------------------------------------------------------------------------
// Kernel 2: per-sample GEMM  out[n] = x[n] (64x128) @ W[s(n)] (128x128)
// 1 block / sample, 4 waves; wave w computes rows [16w, 16w+16).
//
// v2: NO LDS, NO barriers. Wt is 256 KB bf16 -> permanently L2-resident.
// B fragments are loaded straight from global (L2 hit, ~200 cy) inside the
// MFMA loop. This removes the stage->syncthreads->compute phase serialization
// that left the memory pipe idle, and lets the compiler hoist/interleave all
// loads. Extra L2 read traffic (~2 GiB total) is far under the L2 BW ceiling
// and overlaps the HBM stream (x in, out out = the real 1.07 GB bottleneck).
// ---------------------------------------------------------------------------
__global__ __launch_bounds__(256, 4)
void combine_kernel(const float* __restrict__ x,
                    const int* __restrict__ sp,
                    const __hip_bfloat16* __restrict__ Wt,
                    float* __restrict__ out) {
    const int n   = blockIdx.x;
    const int tid = threadIdx.x;
    const int s   = sp[n];                         // uniform -> scalar load

    const int lane = tid & 63;
    const int wave = tid >> 6;
    const int col  = lane & 15;                    // A row / B col / D col
    const int quad = lane >> 4;

    // ---- A fragments straight from global (no reuse across waves) ----
    // A[m = 16*wave + col][k = quad*8 + j + 32*kstep], j contiguous -> 2x float4
    const float* xrow = x + (size_t)n * (NC * DIN) + (wave * 16 + col) * DIN + quad * 8;
    short8 a[4];
    #pragma unroll
    for (int k = 0; k < 4; ++k) {
        const float4* p = reinterpret_cast<const float4*>(xrow + k * 32);
        float4 p0 = p[0];
        float4 p1 = p[1];
        union { short8 v; short2 h[4]; } u;
        union { __hip_bfloat162 b; short2 s2; } c;
        c.b = __float22bfloat162_rn(make_float2(p0.x, p0.y)); u.h[0] = c.s2;
        c.b = __float22bfloat162_rn(make_float2(p0.z, p0.w)); u.h[1] = c.s2;
        c.b = __float22bfloat162_rn(make_float2(p1.x, p1.y)); u.h[2] = c.s2;
        c.b = __float22bfloat162_rn(make_float2(p1.z, p1.w)); u.h[3] = c.s2;
        a[k] = u.v;
    }

    // ---- B fragments direct from L2-resident Wt ----
    // B[k = quad*8 + j + 32*kstep][nq = nt*16 + col] = Wt[s][nt*16+col][quad*8 + 32*kstep + j]
    // Per 16-lane group each load covers whole 64B lines (4 quads contiguous).
    const ushort* wb = reinterpret_cast<const ushort*>(Wt)
                     + (size_t)s * (DIN * DOUT) + col * DIN + quad * 8;

    f32x4 acc[8];
    #pragma unroll
    for (int t = 0; t < 8; ++t) acc[t] = (f32x4){0.f, 0.f, 0.f, 0.f};

    #pragma unroll
    for (int nt = 0; nt < 8; ++nt) {
        const ushort* bp = wb + nt * 16 * DIN;
        #pragma unroll
        for (int k = 0; k < 4; ++k) {
            short8 b = *reinterpret_cast<const short8*>(bp + k * 32);
            acc[nt] = __builtin_amdgcn_mfma_f32_16x16x32_bf16(a[k], b, acc[nt], 0, 0, 0);
        }
    }

    // ---- store: D[row = quad*4 + r][col], 16-lane contiguous 64B segments ----
    // Nontemporal: out is written once and never re-read -> don't pollute L2
    // (keeps Wt + inbound x lines hot).
    float* op = out + (size_t)n * (NC * DOUT) + (wave * 16) * DOUT;
    #pragma unroll
    for (int nt = 0; nt < 8; ++nt) {
        union { f32x4 v; float f[4]; } u;
        u.v = acc[nt];
        #pragma unroll
        for (int r = 0; r < 4; ++r) {
            __builtin_nontemporal_store(u.f[r], &op[(quad * 4 + r) * DOUT + nt * 16 + col]);
        }
    }
}

// ---------------------------------------------------------------------------
extern "C" void kernel_launch(void* const* d_in, const int* in_sizes, int n_in,
                              void* d_out, int out_size, void* d_ws, size_t ws_size,
                              hipStream_t stream) {
    const float* x  = (const float*)d_in[0];   // [16384, 64, 128] fp32
    const int*   sp = (const int*)d_in[1];     // [16384] int
    const float* W  = (const float*)d_in[2];   // [8, 128, 128] fp32
    float* out = (float*)d_out;                // [16384, 64, 128] fp32
    __hip_bfloat16* Wt = (__hip_bfloat16*)d_ws;  // 8*128*128*2 = 256 KB scratch

    wt_transpose_kernel<<<(NSP * DIN * DOUT) / 256, 256, 0, stream>>>(W, Wt);
    combine_kernel<<<NS, 256, 0, stream>>>(x, sp, Wt, out);
}